// Round 4
// baseline (14879.633 us; speedup 1.0000x reference)
//
#include <hip/hip_runtime.h>
#include <hip/hip_bf16.h>

// Problem constants (from reference)
#define HH 512
#define WW 512
#define NN 8192
#define FF 2
#define BB 8
#define MM (NN * FF)      // 16384 splats per batch
#define HW (HH * WW)      // 262144 pixels per batch image
#define TPB 256           // threads per workgroup (4 waves)

// ---- dual-dtype input load: f32mode ? float : bf16 ----
__device__ __forceinline__ float ld(const void* p, int i, int f32mode) {
  if (f32mode) return ((const float*)p)[i];
  unsigned u = ((const unsigned short*)p)[i];
  return __uint_as_float(u << 16);
}

// Abramowitz & Stegun 7.1.26, |err| <= 1.5e-7.
__device__ __forceinline__ float erf_f(float x) {
  float ax = fabsf(x);
  float t = 1.0f / (1.0f + 0.3275911f * ax);
  float y = t * (0.254829592f +
           t * (-0.284496736f +
           t * (1.421413741f +
           t * (-1.453152027f +
           t * 1.061405429f))));
  y = 1.0f - y * __expf(-ax * ax);
  return copysignf(y, x);
}

// K1: detect dtype, then invert the 8 4x4 transforms (Gauss-Jordan), f32.
__global__ void k_inv(const void* __restrict__ T, float* __restrict__ invT,
                      int* __restrict__ flag) {
  int b = threadIdx.x;
  if (b >= BB) return;
  // dtype probe: under f32 data, words 0/5/10 are the diagonal of matrix 0 (≈1).
  const float* Tf = (const float*)T;
  int f32mode = (fabsf(Tf[0] - 1.f) < 0.4f &&
                 fabsf(Tf[5] - 1.f) < 0.4f &&
                 fabsf(Tf[10] - 1.f) < 0.4f) ? 1 : 0;
  if (b == 0) *flag = f32mode;

  float a[4][8];
  for (int r = 0; r < 4; ++r)
    for (int c = 0; c < 4; ++c) {
      a[r][c] = ld(T, b * 16 + r * 4 + c, f32mode);
      a[r][4 + c] = (r == c) ? 1.0f : 0.0f;
    }
  for (int k = 0; k < 4; ++k) {
    int p = k; float best = fabsf(a[k][k]);
    for (int i = k + 1; i < 4; ++i) {
      float v = fabsf(a[i][k]);
      if (v > best) { best = v; p = i; }
    }
    if (p != k)
      for (int c = 0; c < 8; ++c) { float tmp = a[k][c]; a[k][c] = a[p][c]; a[p][c] = tmp; }
    float inv = 1.0f / a[k][k];
    for (int c = 0; c < 8; ++c) a[k][c] *= inv;
    for (int i = 0; i < 4; ++i) {
      if (i == k) continue;
      float f = a[i][k];
      for (int c = 0; c < 8; ++c) a[i][c] -= f * a[k][c];
    }
  }
  for (int r = 0; r < 4; ++r)
    for (int c = 0; c < 4; ++c)
      invT[b * 16 + r * 4 + c] = a[r][4 + c];
}

// K2: build per-(b,m) splat records {row, col, scale, weight}.
__global__ void k_table(const void* __restrict__ centers, const void* __restrict__ scales,
                        const void* __restrict__ weights, const float* __restrict__ invT,
                        const int* __restrict__ flag, float4* __restrict__ table) {
  int idx = blockIdx.x * blockDim.x + threadIdx.x;   // [0, BB*MM)
  if (idx >= BB * MM) return;
  int f32mode = *flag;
  int b = idx >> 14;           // MM = 2^14
  int m = idx & (MM - 1);
  int n = m >> 1;              // FF = 2
  const float* Tb = invT + b * 16;
  float cx = ld(centers, 3 * n, f32mode);
  float cy = ld(centers, 3 * n + 1, f32mode);
  float cz = ld(centers, 3 * n + 2, f32mode);
  float p0 = Tb[0]  * cx + Tb[1]  * cy + Tb[2]  * cz + Tb[3];
  float p1 = Tb[4]  * cx + Tb[5]  * cy + Tb[6]  * cz + Tb[7];
  float p3 = Tb[12] * cx + Tb[13] * cy + Tb[14] * cz + Tb[15];
  float inv = 1.0f / p3;
  float4 rec;
  rec.x = p0 * inv;            // row coordinate (A2P = 1)
  rec.y = p1 * inv;            // col coordinate
  rec.z = ld(scales, m, f32mode);
  rec.w = ld(weights, m, f32mode);
  table[idx] = rec;
}

// K3: tile-gather. One workgroup per 64x64 image tile; accumulate in LDS,
// write bf16/f32 output directly (tiles own disjoint pixels).
__global__ void __launch_bounds__(TPB) k_gather(const float4* __restrict__ table,
                                                const void* __restrict__ bwv,
                                                const int* __restrict__ flag,
                                                void* __restrict__ out) {
  __shared__ float tile[64 * 64];            // 16 KB
  __shared__ unsigned short list[MM];        // 32 KB — full capacity, cannot overflow
  __shared__ int cnt;

  int tid = threadIdx.x;
  int bi  = blockIdx.x;                      // [0, BB*64)
  int b   = bi >> 6;
  int t   = bi & 63;
  int trow = (t >> 3) << 6;                  // tile origin row
  int tcol = (t & 7) << 6;                   // tile origin col
  int f32mode = *flag;

  for (int p = tid; p < 64 * 64; p += TPB) tile[p] = 0.f;
  if (tid == 0) cnt = 0;
  __syncthreads();

  const float4* tb = table + (b << 14);

  // ---- phase 1: scan + compact overlapping records ----
  for (int r = tid; r < MM; r += TPB) {
    float4 rec = tb[r];
    float row = rec.x, col = rec.y, s = rec.z;
    float Rf = 5.0f * s + 0.5f;
    int rlo = max(0, (int)ceilf(row - Rf));
    int rhi = min(HH - 1, (int)floorf(row + Rf));
    int clo = max(0, (int)ceilf(col - Rf));
    int chi = min(WW - 1, (int)floorf(col + Rf));
    bool ov = (rlo <= trow + 63) && (rhi >= trow) &&
              (clo <= tcol + 63) && (chi >= tcol) &&
              (rlo <= rhi) && (clo <= chi);
    if (!ov && !(r & 1)) {
      // bubble-only overlap (clamped 2x2 point-mass window)
      int r0 = (int)floorf(row), c0 = (int)floorf(col);
      int rr0 = min(max(r0, 0), HH - 1), rr1 = min(max(r0 + 1, 0), HH - 1);
      int cc0 = min(max(c0, 0), WW - 1), cc1 = min(max(c0 + 1, 0), WW - 1);
      ov = (rr0 <= trow + 63) && (rr1 >= trow) &&
           (cc0 <= tcol + 63) && (cc1 >= tcol);
    }
    if (ov) {
      int k = atomicAdd(&cnt, 1);
      list[k] = (unsigned short)r;
    }
  }
  __syncthreads();

  // ---- phase 2: wave-cooperative processing into LDS ----
  int lane = tid & 63;
  int wv   = tid >> 6;
  int n_list = cnt;
  for (int j = wv; j < n_list; j += (TPB / 64)) {
    int r = list[j];
    float4 rec = tb[r];
    float row = rec.x, col = rec.y, s = rec.z, w = rec.w;

    // bubble point-mass (even records only; wave-uniform branch)
    if (!(r & 1)) {
      float bw = ld(bwv, r >> 1, f32mode);
      float r0f = floorf(row), c0f = floorf(col);
      float fr = row - r0f, fc = col - c0f;
      int r0 = (int)r0f, c0 = (int)c0f;
      int rr0 = min(max(r0, 0), HH - 1), rr1 = min(max(r0 + 1, 0), HH - 1);
      int cc0 = min(max(c0, 0), WW - 1), cc1 = min(max(c0 + 1, 0), WW - 1);
      int rsel = (lane < 2) ? rr0 : rr1;
      int csel = (lane & 1) ? cc1 : cc0;
      float wr = (lane < 2) ? (1.f - fr) : fr;
      float wc = (lane & 1) ? fc : (1.f - fc);
      if (lane < 4 && rsel >= trow && rsel < trow + 64 &&
          csel >= tcol && csel < tcol + 64)
        atomicAdd(&tile[((rsel - trow) << 6) + (csel - tcol)], bw * wr * wc);
    }

    // separable gaussian window, clipped to image then tile
    float rs = 0.70710678118f / s;           // 1/(s*sqrt(2))
    float Rf = 5.0f * s + 0.5f;
    int rlo = max(trow, (int)ceilf(row - Rf));
    int rhi = min(trow + 63, (int)floorf(row + Rf));
    int clo = max(tcol, (int)ceilf(col - Rf));
    int chi = min(tcol + 63, (int)floorf(col + Rf));
    if (rlo > rhi || clo > chi) continue;
    int nc = chi - clo + 1;                  // <= 43
    int nr = rhi - rlo + 1;                  // <= 43
    float Ew = erf_f(((float)(clo + lane) - 0.5f - col) * rs);
    float pwq = (__shfl_down(Ew, 1) - Ew) * (0.25f * w);
    float Eh = erf_f(((float)(rlo + lane) - 0.5f - row) * rs);
    float Dh = __shfl_down(Eh, 1) - Eh;
    int base = ((rlo - trow) << 6) + (clo - tcol);
    for (int k = 0; k < nr; ++k) {
      float dh = __shfl(Dh, k);
      if (lane < nc)
        atomicAdd(&tile[base + (k << 6) + lane], dh * pwq);
    }
  }
  __syncthreads();

  // ---- phase 3: write tile directly to output ----
  if (f32mode) {
    float* o = (float*)out + ((size_t)b << 18);
    for (int p = tid; p < 64 * 64; p += TPB)
      o[((trow + (p >> 6)) << 9) + tcol + (p & 63)] = tile[p];
  } else {
    unsigned short* o = (unsigned short*)out + ((size_t)b << 18);
    for (int p = tid; p < 64 * 64; p += TPB) {
      __hip_bfloat16 h = __float2bfloat16(tile[p]);
      o[((trow + (p >> 6)) << 9) + tcol + (p & 63)] =
          *reinterpret_cast<unsigned short*>(&h);
    }
  }
}

extern "C" void kernel_launch(void* const* d_in, const int* in_sizes, int n_in,
                              void* d_out, int out_size, void* d_ws, size_t ws_size,
                              hipStream_t stream) {
  const void* T       = d_in[0];   // (B,4,4)
  const void* centers = d_in[1];   // (N,3)
  const void* scales  = d_in[2];   // (N,F)
  const void* weights = d_in[3];   // (N,F)
  const void* bubble  = d_in[4];   // (N,)

  char* ws = (char*)d_ws;
  float4* table = (float4*)ws;                              // 2 MB splat records
  float*  invT  = (float*)(ws + (size_t)BB * MM * 16);      // 512 B
  int*    flag  = (int*)(invT + BB * 16);

  k_inv<<<1, 64, 0, stream>>>(T, invT, flag);
  k_table<<<512, 256, 0, stream>>>(centers, scales, weights, invT, flag, table);
  k_gather<<<BB * 64, TPB, 0, stream>>>(table, bubble, flag, d_out);
}

// Round 6
// 6086.797 us; speedup vs baseline: 2.4446x; 2.4446x over previous
//
#include <hip/hip_runtime.h>
#include <hip/hip_bf16.h>

// Problem constants (from reference)
#define HH 512
#define WW 512
#define NN 8192
#define FF 2
#define BB 8
#define MM (NN * FF)      // 16384 splats per batch
#define HW (HH * WW)      // 262144 pixels per batch image
#define TPB 256           // threads per workgroup (4 waves)
#define CAP 4096          // candidate list capacity == chunk size (overflow impossible)

// ---- dual-dtype input load: f32mode ? float : bf16 ----
__device__ __forceinline__ float ld(const void* p, int i, int f32mode) {
  if (f32mode) return ((const float*)p)[i];
  unsigned u = ((const unsigned short*)p)[i];
  return __uint_as_float(u << 16);
}

// Abramowitz & Stegun 7.1.26, |err| <= 1.5e-7.
__device__ __forceinline__ float erf_f(float x) {
  float ax = fabsf(x);
  float t = 1.0f / (1.0f + 0.3275911f * ax);
  float y = t * (0.254829592f +
           t * (-0.284496736f +
           t * (1.421413741f +
           t * (-1.453152027f +
           t * 1.061405429f))));
  y = 1.0f - y * __expf(-ax * ax);
  return copysignf(y, x);
}

// K1: detect dtype, then invert the 8 4x4 transforms (Gauss-Jordan), f32.
__global__ void k_inv(const void* __restrict__ T, float* __restrict__ invT,
                      int* __restrict__ flag) {
  int b = threadIdx.x;
  if (b >= BB) return;
  const float* Tf = (const float*)T;
  int f32mode = (fabsf(Tf[0] - 1.f) < 0.4f &&
                 fabsf(Tf[5] - 1.f) < 0.4f &&
                 fabsf(Tf[10] - 1.f) < 0.4f) ? 1 : 0;
  if (b == 0) *flag = f32mode;

  float a[4][8];
  for (int r = 0; r < 4; ++r)
    for (int c = 0; c < 4; ++c) {
      a[r][c] = ld(T, b * 16 + r * 4 + c, f32mode);
      a[r][4 + c] = (r == c) ? 1.0f : 0.0f;
    }
  for (int k = 0; k < 4; ++k) {
    int p = k; float best = fabsf(a[k][k]);
    for (int i = k + 1; i < 4; ++i) {
      float v = fabsf(a[i][k]);
      if (v > best) { best = v; p = i; }
    }
    if (p != k)
      for (int c = 0; c < 8; ++c) { float tmp = a[k][c]; a[k][c] = a[p][c]; a[p][c] = tmp; }
    float inv = 1.0f / a[k][k];
    for (int c = 0; c < 8; ++c) a[k][c] *= inv;
    for (int i = 0; i < 4; ++i) {
      if (i == k) continue;
      float f = a[i][k];
      for (int c = 0; c < 8; ++c) a[i][c] -= f * a[k][c];
    }
  }
  for (int r = 0; r < 4; ++r)
    for (int c = 0; c < 4; ++c)
      invT[b * 16 + r * 4 + c] = a[r][4 + c];
}

// K2: build per-(b,m) splat records {row, col, scale, weight}.
__global__ void k_table(const void* __restrict__ centers, const void* __restrict__ scales,
                        const void* __restrict__ weights, const float* __restrict__ invT,
                        const int* __restrict__ flag, float4* __restrict__ table) {
  int idx = blockIdx.x * blockDim.x + threadIdx.x;   // [0, BB*MM)
  if (idx >= BB * MM) return;
  int f32mode = *flag;
  int b = idx >> 14;           // MM = 2^14
  int m = idx & (MM - 1);
  int n = m >> 1;              // FF = 2
  const float* Tb = invT + b * 16;
  float cx = ld(centers, 3 * n, f32mode);
  float cy = ld(centers, 3 * n + 1, f32mode);
  float cz = ld(centers, 3 * n + 2, f32mode);
  float p0 = Tb[0]  * cx + Tb[1]  * cy + Tb[2]  * cz + Tb[3];
  float p1 = Tb[4]  * cx + Tb[5]  * cy + Tb[6]  * cz + Tb[7];
  float p3 = Tb[12] * cx + Tb[13] * cy + Tb[14] * cz + Tb[15];
  float inv = 1.0f / p3;
  float4 rec;
  rec.x = p0 * inv;            // row coordinate (A2P = 1)
  rec.y = p1 * inv;            // col coordinate
  rec.z = ld(scales, m, f32mode);
  rec.w = ld(weights, m, f32mode);
  table[idx] = rec;
}

// K3: strip-gather with register accumulation. One workgroup per 16-row x 64-col
// strip (grid = BB*64 tiles * 4 strips = 2048). Wave w owns 4 rows, col = lane,
// acc[4] f32 regs. Records scanned in CAP-sized chunks -> list overflow is
// structurally impossible. LDS: 4 KB bubble strip-tile + 8 KB list.
__global__ void __launch_bounds__(TPB) k_gather(const float4* __restrict__ table,
                                                const void* __restrict__ bwv,
                                                const int* __restrict__ flag,
                                                void* __restrict__ out) {
  __shared__ float btile[16 * 64];           // bubbles only, 4 KB
  __shared__ unsigned short list[CAP];       // 8 KB
  __shared__ int cnt;

  int tid = threadIdx.x;
  int bi  = blockIdx.x;                      // [0, BB*256)
  int b   = bi >> 8;
  int rem = bi & 255;
  int t   = rem >> 2;                        // tile [0,64)
  int sub = rem & 3;                         // strip within tile
  int trow = ((t >> 3) << 6) + (sub << 4);   // strip origin row (16 rows)
  int tcol = (t & 7) << 6;                   // tile origin col (64 cols)
  int f32mode = *flag;

  for (int p = tid; p < 16 * 64; p += TPB) btile[p] = 0.f;

  const float4* tb = table + (b << 14);

  int lane = tid & 63;
  int wv   = tid >> 6;
  int srow = trow + (wv << 2);               // this wave's 4-row origin
  float acc[4] = {0.f, 0.f, 0.f, 0.f};
  float colx = (float)(tcol + lane);         // this lane's column

  for (int base = 0; base < MM; base += CAP) {
    __syncthreads();                         // protect cnt/btile from prior phase
    if (tid == 0) cnt = 0;
    __syncthreads();

    // ---- phase 1: scan chunk, compact strip-overlapping records ----
    for (int r = base + tid; r < base + CAP; r += TPB) {
      float4 rec = tb[r];
      float row = rec.x, col = rec.y, s = rec.z;
      float Rf = 5.0f * s + 0.5f;
      int rlo = max(0, (int)ceilf(row - Rf));
      int rhi = min(HH - 1, (int)floorf(row + Rf));
      int clo = max(0, (int)ceilf(col - Rf));
      int chi = min(WW - 1, (int)floorf(col + Rf));
      bool ov = (rlo <= trow + 15) && (rhi >= trow) &&
                (clo <= tcol + 63) && (chi >= tcol) &&
                (rlo <= rhi) && (clo <= chi);
      if (!ov && !(r & 1)) {
        // bubble-only overlap (clamped 2x2 point-mass window)
        int r0 = (int)floorf(row), c0 = (int)floorf(col);
        int rr0 = min(max(r0, 0), HH - 1), rr1 = min(max(r0 + 1, 0), HH - 1);
        int cc0 = min(max(c0, 0), WW - 1), cc1 = min(max(c0 + 1, 0), WW - 1);
        ov = (rr0 <= trow + 15) && (rr1 >= trow) &&
             (cc0 <= tcol + 63) && (cc1 >= tcol);
      }
      if (ov) {
        int k = atomicAdd(&cnt, 1);          // k < CAP by construction
        list[k] = (unsigned short)r;
      }
    }
    __syncthreads();

    // ---- phase 2: all waves walk the list; each accumulates its 4 rows ----
    int n_list = cnt;
    for (int j = 0; j < n_list; ++j) {
      int r = list[j];
      float4 rec = tb[r];
      float row = rec.x, col = rec.y, s = rec.z, w = rec.w;

      // bubble point-mass: wave 0 handles all even records (LDS atomics, rare)
      if (wv == 0 && !(r & 1)) {
        float bw = ld(bwv, r >> 1, f32mode);
        float r0f = floorf(row), c0f = floorf(col);
        float fr = row - r0f, fc = col - c0f;
        int r0 = (int)r0f, c0 = (int)c0f;
        int rr0 = min(max(r0, 0), HH - 1), rr1 = min(max(r0 + 1, 0), HH - 1);
        int cc0 = min(max(c0, 0), WW - 1), cc1 = min(max(c0 + 1, 0), WW - 1);
        int rsel = (lane < 2) ? rr0 : rr1;
        int csel = (lane & 1) ? cc1 : cc0;
        float wr = (lane < 2) ? (1.f - fr) : fr;
        float wc = (lane & 1) ? fc : (1.f - fc);
        if (lane < 4 && rsel >= trow && rsel < trow + 16 &&
            csel >= tcol && csel < tcol + 64)
          atomicAdd(&btile[((rsel - trow) << 6) + (csel - tcol)], bw * wr * wc);
      }

      float rs = 0.70710678118f / s;         // 1/(s*sqrt(2))
      float Rf = 5.0f * s + 0.5f;
      // wave-uniform skip vs this wave's 4 rows / tile cols
      if (row - Rf > (float)(srow + 3) || row + Rf < (float)srow ||
          col - Rf > (float)(tcol + 63) || col + Rf < (float)tcol) continue;

      // column profile at this lane's column (0.25*w folded in)
      float lo = (colx - 0.5f - col) * rs;
      float hi = (colx + 0.5f - col) * rs;
      float pc = (erf_f(hi) - erf_f(lo)) * (0.25f * w);
      // row boundary erfs: lanes 0..4 hold E at srow+lane-0.5
      float Eh = erf_f(((float)(srow + lane) - 0.5f - row) * rs);
      float Dh = __shfl_down(Eh, 1) - Eh;    // lane k: delta of row srow+k
#pragma unroll
      for (int k = 0; k < 4; ++k)
        acc[k] += pc * __shfl(Dh, k);
    }
  }
  __syncthreads();

  // ---- phase 3: combine with bubble tile, write strip directly ----
  if (f32mode) {
    float* o = (float*)out + ((size_t)b << 18);
#pragma unroll
    for (int k = 0; k < 4; ++k) {
      int rr = srow + k;
      o[(rr << 9) + tcol + lane] = acc[k] + btile[((rr - trow) << 6) + lane];
    }
  } else {
    unsigned short* o = (unsigned short*)out + ((size_t)b << 18);
#pragma unroll
    for (int k = 0; k < 4; ++k) {
      int rr = srow + k;
      float v = acc[k] + btile[((rr - trow) << 6) + lane];
      __hip_bfloat16 h = __float2bfloat16(v);
      o[(rr << 9) + tcol + lane] = *reinterpret_cast<unsigned short*>(&h);
    }
  }
}

extern "C" void kernel_launch(void* const* d_in, const int* in_sizes, int n_in,
                              void* d_out, int out_size, void* d_ws, size_t ws_size,
                              hipStream_t stream) {
  const void* T       = d_in[0];   // (B,4,4)
  const void* centers = d_in[1];   // (N,3)
  const void* scales  = d_in[2];   // (N,F)
  const void* weights = d_in[3];   // (N,F)
  const void* bubble  = d_in[4];   // (N,)

  char* ws = (char*)d_ws;
  float4* table = (float4*)ws;                              // 2 MB splat records
  float*  invT  = (float*)(ws + (size_t)BB * MM * 16);      // 512 B
  int*    flag  = (int*)(invT + BB * 16);

  k_inv<<<1, 64, 0, stream>>>(T, invT, flag);
  k_table<<<512, 256, 0, stream>>>(centers, scales, weights, invT, flag, table);
  k_gather<<<BB * 256, TPB, 0, stream>>>(table, bubble, flag, d_out);
}

// Round 7
// 4935.875 us; speedup vs baseline: 3.0146x; 1.2332x over previous
//
#include <hip/hip_runtime.h>
#include <hip/hip_bf16.h>

// Problem constants (from reference)
#define HH 512
#define WW 512
#define NN 8192
#define FF 2
#define BB 8
#define MM (NN * FF)      // 16384 splats per batch
#define HW (HH * WW)      // 262144 pixels per batch image
#define TPB 256           // threads per workgroup (4 waves)
#define CAP 1024          // chunk size == list capacity (overflow impossible)

// ---- dual-dtype input load: f32mode ? float : bf16 ----
__device__ __forceinline__ float ld(const void* p, int i, int f32mode) {
  if (f32mode) return ((const float*)p)[i];
  unsigned u = ((const unsigned short*)p)[i];
  return __uint_as_float(u << 16);
}

// Abramowitz & Stegun 7.1.26, |err| <= 1.5e-7.
__device__ __forceinline__ float erf_f(float x) {
  float ax = fabsf(x);
  float t = 1.0f / (1.0f + 0.3275911f * ax);
  float y = t * (0.254829592f +
           t * (-0.284496736f +
           t * (1.421413741f +
           t * (-1.453152027f +
           t * 1.061405429f))));
  y = 1.0f - y * __expf(-ax * ax);
  return copysignf(y, x);
}

// K1: detect dtype, then invert the 8 4x4 transforms (Gauss-Jordan), f32.
__global__ void k_inv(const void* __restrict__ T, float* __restrict__ invT,
                      int* __restrict__ flag) {
  int b = threadIdx.x;
  if (b >= BB) return;
  const float* Tf = (const float*)T;
  int f32mode = (fabsf(Tf[0] - 1.f) < 0.4f &&
                 fabsf(Tf[5] - 1.f) < 0.4f &&
                 fabsf(Tf[10] - 1.f) < 0.4f) ? 1 : 0;
  if (b == 0) *flag = f32mode;

  float a[4][8];
  for (int r = 0; r < 4; ++r)
    for (int c = 0; c < 4; ++c) {
      a[r][c] = ld(T, b * 16 + r * 4 + c, f32mode);
      a[r][4 + c] = (r == c) ? 1.0f : 0.0f;
    }
  for (int k = 0; k < 4; ++k) {
    int p = k; float best = fabsf(a[k][k]);
    for (int i = k + 1; i < 4; ++i) {
      float v = fabsf(a[i][k]);
      if (v > best) { best = v; p = i; }
    }
    if (p != k)
      for (int c = 0; c < 8; ++c) { float tmp = a[k][c]; a[k][c] = a[p][c]; a[p][c] = tmp; }
    float inv = 1.0f / a[k][k];
    for (int c = 0; c < 8; ++c) a[k][c] *= inv;
    for (int i = 0; i < 4; ++i) {
      if (i == k) continue;
      float f = a[i][k];
      for (int c = 0; c < 8; ++c) a[i][c] -= f * a[k][c];
    }
  }
  for (int r = 0; r < 4; ++r)
    for (int c = 0; c < 4; ++c)
      invT[b * 16 + r * 4 + c] = a[r][4 + c];
}

// K2: build per-(b,m) splat records {row, col, scale, weight}.
__global__ void k_table(const void* __restrict__ centers, const void* __restrict__ scales,
                        const void* __restrict__ weights, const float* __restrict__ invT,
                        const int* __restrict__ flag, float4* __restrict__ table) {
  int idx = blockIdx.x * blockDim.x + threadIdx.x;   // [0, BB*MM)
  if (idx >= BB * MM) return;
  int f32mode = *flag;
  int b = idx >> 14;           // MM = 2^14
  int m = idx & (MM - 1);
  int n = m >> 1;              // FF = 2
  const float* Tb = invT + b * 16;
  float cx = ld(centers, 3 * n, f32mode);
  float cy = ld(centers, 3 * n + 1, f32mode);
  float cz = ld(centers, 3 * n + 2, f32mode);
  float p0 = Tb[0]  * cx + Tb[1]  * cy + Tb[2]  * cz + Tb[3];
  float p1 = Tb[4]  * cx + Tb[5]  * cy + Tb[6]  * cz + Tb[7];
  float p3 = Tb[12] * cx + Tb[13] * cy + Tb[14] * cz + Tb[15];
  float inv = 1.0f / p3;
  float4 rec;
  rec.x = p0 * inv;            // row coordinate (A2P = 1)
  rec.y = p1 * inv;            // col coordinate
  rec.z = ld(scales, m, f32mode);
  rec.w = ld(weights, m, f32mode);
  table[idx] = rec;
}

// K3: strip-gather, register accumulation. One workgroup per 16x64 strip
// (grid 2048, blockIdx swizzled to break hot-strip -> same-CU aliasing).
// Bubbles: direct per-thread pass into LDS btile (NOT via the list — the
// corner clamp pile-up (~41% of records clamp to (0,0)) floods lists otherwise).
// Gaussians: chunked scan compacts full records into LDS, then all 4 waves
// walk the LDS list (no global pointer-chase). LDS: 4 KB btile + 16 KB list.
__global__ void __launch_bounds__(TPB) k_gather(const float4* __restrict__ table,
                                                const void* __restrict__ bwv,
                                                const int* __restrict__ flag,
                                                void* __restrict__ out) {
  __shared__ float btile[16 * 64];           // bubbles only, 4 KB
  __shared__ float4 lrec[CAP];               // compacted records, 16 KB
  __shared__ int cnt;

  int tid = threadIdx.x;
  int bi  = (blockIdx.x * 997) & (BB * 256 - 1);   // odd-multiplier swizzle
  int b   = bi >> 8;
  int rem = bi & 255;
  int t   = rem >> 2;                        // tile [0,64)
  int sub = rem & 3;                         // strip within tile
  int trow = ((t >> 3) << 6) + (sub << 4);   // strip origin row (16 rows)
  int tcol = (t & 7) << 6;                   // tile origin col (64 cols)
  int f32mode = *flag;

  for (int p = tid; p < 16 * 64; p += TPB) btile[p] = 0.f;
  __syncthreads();                           // zeroing before bubble atomics

  const float4* tb = table + (b << 14);

  // ---- bubble direct pass: per-thread over even records ----
  for (int n = tid; n < NN; n += TPB) {
    float4 rec = tb[2 * n];
    float row = rec.x, col = rec.y;
    float r0f = floorf(row), c0f = floorf(col);
    int r0 = (int)r0f, c0 = (int)c0f;
    int rr0 = min(max(r0, 0), HH - 1), rr1 = min(max(r0 + 1, 0), HH - 1);
    int cc0 = min(max(c0, 0), WW - 1), cc1 = min(max(c0 + 1, 0), WW - 1);
    // quick reject vs this strip
    if (rr1 < trow || rr0 > trow + 15 || cc1 < tcol || cc0 > tcol + 63) continue;
    float bw = ld(bwv, n, f32mode);
    float fr = row - r0f, fc = col - c0f;
    float w00 = bw * (1.f - fr) * (1.f - fc);
    float w01 = bw * (1.f - fr) * fc;
    float w10 = bw * fr * (1.f - fc);
    float w11 = bw * fr * fc;
    if (rr0 >= trow && rr0 <= trow + 15) {
      if (cc0 >= tcol && cc0 <= tcol + 63)
        atomicAdd(&btile[((rr0 - trow) << 6) + (cc0 - tcol)], w00);
      if (cc1 >= tcol && cc1 <= tcol + 63)
        atomicAdd(&btile[((rr0 - trow) << 6) + (cc1 - tcol)], w01);
    }
    if (rr1 >= trow && rr1 <= trow + 15) {
      if (cc0 >= tcol && cc0 <= tcol + 63)
        atomicAdd(&btile[((rr1 - trow) << 6) + (cc0 - tcol)], w10);
      if (cc1 >= tcol && cc1 <= tcol + 63)
        atomicAdd(&btile[((rr1 - trow) << 6) + (cc1 - tcol)], w11);
    }
  }

  // ---- gaussian gather: chunked scan + LDS-list walk ----
  int lane = tid & 63;
  int wv   = tid >> 6;
  int srow = trow + (wv << 2);               // this wave's 4-row origin
  float acc[4] = {0.f, 0.f, 0.f, 0.f};
  float colx = (float)(tcol + lane);         // this lane's column

  for (int base = 0; base < MM; base += CAP) {
    __syncthreads();
    if (tid == 0) cnt = 0;
    __syncthreads();

    // phase 1: scan chunk, compact overlapping records (full payload) to LDS
    for (int r = base + tid; r < base + CAP; r += TPB) {
      float4 rec = tb[r];
      float row = rec.x, col = rec.y, s = rec.z;
      float Rf = 5.0f * s + 0.5f;
      int rlo = max(0, (int)ceilf(row - Rf));
      int rhi = min(HH - 1, (int)floorf(row + Rf));
      int clo = max(0, (int)ceilf(col - Rf));
      int chi = min(WW - 1, (int)floorf(col + Rf));
      bool ov = (rlo <= trow + 15) && (rhi >= trow) &&
                (clo <= tcol + 63) && (chi >= tcol) &&
                (rlo <= rhi) && (clo <= chi);
      if (ov) {
        int k = atomicAdd(&cnt, 1);          // k < CAP by construction
        float4 l;
        l.x = row; l.y = col;
        l.z = 0.70710678118f / s;            // rs
        l.w = 0.25f * rec.w;                 // quarter-weight folded
        lrec[k] = l;
      }
    }
    __syncthreads();

    // phase 2: all waves walk the LDS list; each accumulates its 4 rows
    int n_list = cnt;
    for (int j = 0; j < n_list; ++j) {
      float4 rec = lrec[j];
      float row = rec.x, col = rec.y, rs = rec.z, wq = rec.w;
      float Rf = 3.53553391f / rs + 0.5f;    // 5*s + 0.5
      // wave-uniform skip vs this wave's 4 rows / tile cols
      if (row - Rf > (float)(srow + 3) || row + Rf < (float)srow ||
          col - Rf > (float)(tcol + 63) || col + Rf < (float)tcol) continue;

      float lo = (colx - 0.5f - col) * rs;
      float hi = (colx + 0.5f - col) * rs;
      float pc = (erf_f(hi) - erf_f(lo)) * wq;
      // row boundary erfs: lanes 0..4 hold E at srow+lane-0.5
      float Eh = erf_f(((float)(srow + lane) - 0.5f - row) * rs);
      float Dh = __shfl_down(Eh, 1) - Eh;    // lane k: delta of row srow+k
#pragma unroll
      for (int k = 0; k < 4; ++k)
        acc[k] += pc * __shfl(Dh, k);
    }
  }
  __syncthreads();

  // ---- combine with bubble tile, write strip directly ----
  if (f32mode) {
    float* o = (float*)out + ((size_t)b << 18);
#pragma unroll
    for (int k = 0; k < 4; ++k) {
      int rr = srow + k;
      o[(rr << 9) + tcol + lane] = acc[k] + btile[((rr - trow) << 6) + lane];
    }
  } else {
    unsigned short* o = (unsigned short*)out + ((size_t)b << 18);
#pragma unroll
    for (int k = 0; k < 4; ++k) {
      int rr = srow + k;
      float v = acc[k] + btile[((rr - trow) << 6) + lane];
      __hip_bfloat16 h = __float2bfloat16(v);
      o[(rr << 9) + tcol + lane] = *reinterpret_cast<unsigned short*>(&h);
    }
  }
}

extern "C" void kernel_launch(void* const* d_in, const int* in_sizes, int n_in,
                              void* d_out, int out_size, void* d_ws, size_t ws_size,
                              hipStream_t stream) {
  const void* T       = d_in[0];   // (B,4,4)
  const void* centers = d_in[1];   // (N,3)
  const void* scales  = d_in[2];   // (N,F)
  const void* weights = d_in[3];   // (N,F)
  const void* bubble  = d_in[4];   // (N,)

  char* ws = (char*)d_ws;
  float4* table = (float4*)ws;                              // 2 MB splat records
  float*  invT  = (float*)(ws + (size_t)BB * MM * 16);      // 512 B
  int*    flag  = (int*)(invT + BB * 16);

  k_inv<<<1, 64, 0, stream>>>(T, invT, flag);
  k_table<<<512, 256, 0, stream>>>(centers, scales, weights, invT, flag, table);
  k_gather<<<BB * 256, TPB, 0, stream>>>(table, bubble, flag, d_out);
}

// Round 8
// 4855.984 us; speedup vs baseline: 3.0642x; 1.0165x over previous
//
#include <hip/hip_runtime.h>
#include <hip/hip_bf16.h>

// Problem constants (from reference)
#define HH 512
#define WW 512
#define NN 8192
#define FF 2
#define BB 8
#define MM (NN * FF)        // 16384 splats per batch
#define BANDS 64            // 8-row bands per image
#define NBIN (BB * BANDS)   // 512 gaussian bins; bubble bins are NBIN..2*NBIN-1
#define ECAP 1100000        // entries capacity (structural max 1,048,576)

// ---- dual-dtype input load: f32mode ? float : bf16 ----
__device__ __forceinline__ float ld(const void* p, int i, int f32mode) {
  if (f32mode) return ((const float*)p)[i];
  unsigned u = ((const unsigned short*)p)[i];
  return __uint_as_float(u << 16);
}

// Abramowitz & Stegun 7.1.26, |err| <= 1.5e-7.
__device__ __forceinline__ float erf_f(float x) {
  float ax = fabsf(x);
  float t = 1.0f / (1.0f + 0.3275911f * ax);
  float y = t * (0.254829592f +
           t * (-0.284496736f +
           t * (1.421413741f +
           t * (-1.453152027f +
           t * 1.061405429f))));
  y = 1.0f - y * __expf(-ax * ax);
  return copysignf(y, x);
}

// Shared by k_count / k_fill — MUST be identical in both (count==fill parity).
struct GRange { int blo, bhi; bool ok; };
__device__ __forceinline__ GRange grange(float row, float col, float s) {
  float Rf = 5.0f * s + 0.5f;
  int rlo = max(0, (int)ceilf(row - Rf));
  int rhi = min(HH - 1, (int)floorf(row + Rf));
  int clo = max(0, (int)ceilf(col - Rf));
  int chi = min(WW - 1, (int)floorf(col + Rf));
  GRange g;
  g.ok  = (rlo <= rhi) && (clo <= chi);
  g.blo = rlo >> 3;
  g.bhi = rhi >> 3;
  return g;
}
struct BRange { int rr0, rr1, cc0, cc1; bool corner; };
__device__ __forceinline__ BRange brange(float row, float col) {
  int r0 = (int)floorf(row), c0 = (int)floorf(col);
  BRange x;
  x.rr0 = min(max(r0, 0), HH - 1);     x.rr1 = min(max(r0 + 1, 0), HH - 1);
  x.cc0 = min(max(c0, 0), WW - 1);     x.cc1 = min(max(c0 + 1, 0), WW - 1);
  x.corner = (row < 0.f) && (col < 0.f);   // all 4 px clamp to (0,0), mass = bw
  return x;
}

// K1: detect dtype, invert the 8 4x4 transforms (Gauss-Jordan), f32.
__global__ void k_inv(const void* __restrict__ T, float* __restrict__ invT,
                      int* __restrict__ flag) {
  int b = threadIdx.x;
  if (b >= BB) return;
  const float* Tf = (const float*)T;
  int f32mode = (fabsf(Tf[0] - 1.f) < 0.4f &&
                 fabsf(Tf[5] - 1.f) < 0.4f &&
                 fabsf(Tf[10] - 1.f) < 0.4f) ? 1 : 0;
  if (b == 0) *flag = f32mode;

  float a[4][8];
  for (int r = 0; r < 4; ++r)
    for (int c = 0; c < 4; ++c) {
      a[r][c] = ld(T, b * 16 + r * 4 + c, f32mode);
      a[r][4 + c] = (r == c) ? 1.0f : 0.0f;
    }
  for (int k = 0; k < 4; ++k) {
    int p = k; float best = fabsf(a[k][k]);
    for (int i = k + 1; i < 4; ++i) {
      float v = fabsf(a[i][k]);
      if (v > best) { best = v; p = i; }
    }
    if (p != k)
      for (int c = 0; c < 8; ++c) { float tmp = a[k][c]; a[k][c] = a[p][c]; a[p][c] = tmp; }
    float inv = 1.0f / a[k][k];
    for (int c = 0; c < 8; ++c) a[k][c] *= inv;
    for (int i = 0; i < 4; ++i) {
      if (i == k) continue;
      float f = a[i][k];
      for (int c = 0; c < 8; ++c) a[i][c] -= f * a[k][c];
    }
  }
  for (int r = 0; r < 4; ++r)
    for (int c = 0; c < 4; ++c)
      invT[b * 16 + r * 4 + c] = a[r][4 + c];
}

// K2: build records {row,col,scale,weight}; also zero bin counters + corner accums.
__global__ void k_table(const void* __restrict__ centers, const void* __restrict__ scales,
                        const void* __restrict__ weights, const float* __restrict__ invT,
                        const int* __restrict__ flag, float4* __restrict__ table,
                        int* __restrict__ cnt, float* __restrict__ corner) {
  int idx = blockIdx.x * blockDim.x + threadIdx.x;   // [0, BB*MM)
  if (idx < 2 * NBIN) cnt[idx] = 0;
  if (idx < BB) corner[idx] = 0.f;
  if (idx >= BB * MM) return;
  int f32mode = *flag;
  int b = idx >> 14;
  int m = idx & (MM - 1);
  int n = m >> 1;
  const float* Tb = invT + b * 16;
  float cx = ld(centers, 3 * n, f32mode);
  float cy = ld(centers, 3 * n + 1, f32mode);
  float cz = ld(centers, 3 * n + 2, f32mode);
  float p0 = Tb[0]  * cx + Tb[1]  * cy + Tb[2]  * cz + Tb[3];
  float p1 = Tb[4]  * cx + Tb[5]  * cy + Tb[6]  * cz + Tb[7];
  float p3 = Tb[12] * cx + Tb[13] * cy + Tb[14] * cz + Tb[15];
  float inv = 1.0f / p3;
  float4 rec;
  rec.x = p0 * inv;
  rec.y = p1 * inv;
  rec.z = ld(scales, m, f32mode);
  rec.w = ld(weights, m, f32mode);
  table[idx] = rec;
}

// K3: count entries per bin; wave-reduce corner-clamped bubble mass.
__global__ void k_count(const float4* __restrict__ table, const void* __restrict__ bwv,
                        const int* __restrict__ flag, int* __restrict__ cnt,
                        float* __restrict__ corner) {
  int idx = blockIdx.x * blockDim.x + threadIdx.x;   // exact grid: BB*MM
  int f32mode = *flag;
  int b = idx >> 14;
  int m = idx & (MM - 1);
  float4 rec = table[idx];
  GRange g = grange(rec.x, rec.y, rec.z);
  if (g.ok)
    for (int band = g.blo; band <= g.bhi; ++band)
      atomicAdd(&cnt[b * BANDS + band], 1);
  float cv = 0.f;
  if (!(m & 1)) {
    BRange x = brange(rec.x, rec.y);
    if (x.corner) {
      cv = ld(bwv, m >> 1, f32mode);
    } else {
      int blo = x.rr0 >> 3, bhi = x.rr1 >> 3;
      atomicAdd(&cnt[NBIN + b * BANDS + blo], 1);
      if (bhi != blo) atomicAdd(&cnt[NBIN + b * BANDS + bhi], 1);
    }
  }
  // full-wave reduce (b is wave-uniform: 16384 % 64 == 0)
  for (int o = 32; o; o >>= 1) cv += __shfl_down(cv, o);
  if ((threadIdx.x & 63) == 0 && cv != 0.f) atomicAdd(&corner[b], cv);
}

// K4: exclusive scan of the 1024 bin counts (single workgroup).
__global__ void k_offsets(const int* __restrict__ cnt, int* __restrict__ off,
                          int* __restrict__ cursor) {
  __shared__ int sc[2 * NBIN];
  int tid = threadIdx.x;
  int c = cnt[tid];
  sc[tid] = c;
  __syncthreads();
  for (int d = 1; d < 2 * NBIN; d <<= 1) {
    int v = (tid >= d) ? sc[tid - d] : 0;
    __syncthreads();
    sc[tid] += v;
    __syncthreads();
  }
  int excl = sc[tid] - c;
  off[tid] = excl;
  cursor[tid] = excl;
  if (tid == 2 * NBIN - 1) off[2 * NBIN] = sc[tid];
}

// K5: fill bin entries. Gaussian payload (row,col,rs,w/4); bubble (row,col,bw,0).
__global__ void k_fill(const float4* __restrict__ table, const void* __restrict__ bwv,
                       const int* __restrict__ flag, int* __restrict__ cursor,
                       float4* __restrict__ entries) {
  int idx = blockIdx.x * blockDim.x + threadIdx.x;
  int f32mode = *flag;
  int b = idx >> 14;
  int m = idx & (MM - 1);
  float4 rec = table[idx];
  GRange g = grange(rec.x, rec.y, rec.z);
  if (g.ok) {
    float4 p;
    p.x = rec.x; p.y = rec.y;
    p.z = 0.70710678118f / rec.z;            // rs = 1/(s*sqrt(2))
    p.w = 0.25f * rec.w;                     // quarter-weight folded
    for (int band = g.blo; band <= g.bhi; ++band) {
      int slot = atomicAdd(&cursor[b * BANDS + band], 1);
      if (slot < ECAP) entries[slot] = p;
    }
  }
  if (!(m & 1)) {
    BRange x = brange(rec.x, rec.y);
    if (!x.corner) {
      float4 p;
      p.x = rec.x; p.y = rec.y;
      p.z = ld(bwv, m >> 1, f32mode);
      p.w = 0.f;
      int blo = x.rr0 >> 3, bhi = x.rr1 >> 3;
      int slot = atomicAdd(&cursor[NBIN + b * BANDS + blo], 1);
      if (slot < ECAP) entries[slot] = p;
      if (bhi != blo) {
        slot = atomicAdd(&cursor[NBIN + b * BANDS + bhi], 1);
        if (slot < ECAP) entries[slot] = p;
      }
    }
  }
}

// K6: LDS-free gather. One wave per 8x64 strip (4096 waves), swizzled.
// Walk the band's gaussian + bubble lists with coalesced 64-wide loads and
// readlane broadcasts; acc[8] f32 registers (col = lane); direct output write.
__global__ void __launch_bounds__(256) k_gather(const float4* __restrict__ entries,
                                                const int* __restrict__ off,
                                                const float* __restrict__ corner,
                                                const int* __restrict__ flag,
                                                void* __restrict__ out) {
  int gw = (blockIdx.x << 2) | (threadIdx.x >> 6);   // global wave id [0,4096)
  int lane = threadIdx.x & 63;
  int strip = (gw * 997) & 4095;                     // odd-mult bijective swizzle
  int b    = strip >> 9;
  int band = (strip >> 3) & 63;
  int tile = strip & 7;
  int srow = band << 3;
  int tcol = tile << 6;
  float colx = (float)(tcol + lane);
  float ccen = (float)tcol + 31.5f;
  float acc[8] = {0.f, 0.f, 0.f, 0.f, 0.f, 0.f, 0.f, 0.f};

  // ---- gaussian list ----
  int gbin = b * BANDS + band;
  int s0 = off[gbin], s1 = off[gbin + 1];
  for (int base = s0; base < s1; base += 64) {
    int nrem = min(64, s1 - base);
    float4 p = entries[base + min(lane, nrem - 1)];
    for (int k = 0; k < nrem; ++k) {
      float row = __shfl(p.x, k), col = __shfl(p.y, k);
      float rs  = __shfl(p.z, k);
      float Rf  = 3.53553391f / rs + 0.5f;           // 5*s + 0.5
      if (fabsf(col - ccen) > 31.5f + Rf) continue;  // wave-uniform col skip
      float wq  = __shfl(p.w, k);
      float lo = (colx - 0.5f - col) * rs;
      float hi = (colx + 0.5f - col) * rs;
      float pc = (erf_f(hi) - erf_f(lo)) * wq;
      float Eh = erf_f(((float)(srow + lane) - 0.5f - row) * rs);
      float Dh = __shfl_down(Eh, 1) - Eh;            // lane j: delta of row srow+j
#pragma unroll
      for (int kk = 0; kk < 8; ++kk)
        acc[kk] += pc * __shfl(Dh, kk);
    }
  }

  // ---- bubble list ----
  int bbin = NBIN + b * BANDS + band;
  s0 = off[bbin]; s1 = off[bbin + 1];
  for (int base = s0; base < s1; base += 64) {
    int nrem = min(64, s1 - base);
    float4 p = entries[base + min(lane, nrem - 1)];
    for (int k = 0; k < nrem; ++k) {
      float row = __shfl(p.x, k), col = __shfl(p.y, k), bw = __shfl(p.z, k);
      float r0f = floorf(row), c0f = floorf(col);
      int r0 = (int)r0f, c0 = (int)c0f;
      int rr0 = min(max(r0, 0), HH - 1), rr1 = min(max(r0 + 1, 0), HH - 1);
      int cc0 = min(max(c0, 0), WW - 1), cc1 = min(max(c0 + 1, 0), WW - 1);
      if (cc1 < tcol || cc0 > tcol + 63) continue;
      float fr = row - r0f, fc = col - c0f;
      int k0 = rr0 - srow, k1 = rr1 - srow;          // in [0,8) when in-strip
      float ca = ((lane == cc0 - tcol) ? bw * (1.f - fr) * (1.f - fc) : 0.f)
               + ((lane == cc1 - tcol) ? bw * (1.f - fr) * fc : 0.f);
      float cb = ((lane == cc0 - tcol) ? bw * fr * (1.f - fc) : 0.f)
               + ((lane == cc1 - tcol) ? bw * fr * fc : 0.f);
#pragma unroll
      for (int kk = 0; kk < 8; ++kk)
        acc[kk] += (kk == k0 ? ca : 0.f) + (kk == k1 ? cb : 0.f);
    }
  }

  // corner-clamped bubble mass (all at pixel (0,0))
  if (band == 0 && tile == 0 && lane == 0) acc[0] += corner[b];

  // ---- write strip (disjoint across waves) ----
  if (*flag) {
    float* o = (float*)out + ((size_t)b << 18);
#pragma unroll
    for (int kk = 0; kk < 8; ++kk)
      o[((srow + kk) << 9) + tcol + lane] = acc[kk];
  } else {
    unsigned short* o = (unsigned short*)out + ((size_t)b << 18);
#pragma unroll
    for (int kk = 0; kk < 8; ++kk) {
      __hip_bfloat16 h = __float2bfloat16(acc[kk]);
      o[((srow + kk) << 9) + tcol + lane] = *reinterpret_cast<unsigned short*>(&h);
    }
  }
}

extern "C" void kernel_launch(void* const* d_in, const int* in_sizes, int n_in,
                              void* d_out, int out_size, void* d_ws, size_t ws_size,
                              hipStream_t stream) {
  const void* T       = d_in[0];   // (B,4,4)
  const void* centers = d_in[1];   // (N,3)
  const void* scales  = d_in[2];   // (N,F)
  const void* weights = d_in[3];   // (N,F)
  const void* bubble  = d_in[4];   // (N,)

  char* ws = (char*)d_ws;
  float4* table   = (float4*)ws;                             // 2,097,152 B
  float4* entries = (float4*)(ws + 2097152);                 // 17,600,000 B
  char*   tail    = ws + 2097152 + (size_t)ECAP * 16;
  float*  invT    = (float*)tail;                            // 512 B
  int*    flag    = (int*)(tail + 512);                      // 4 B (+pad)
  float*  corner  = (float*)(tail + 528);                    // 32 B
  int*    cnt     = (int*)(tail + 560);                      // 4096 B
  int*    off     = (int*)(tail + 4656);                     // 4100 B
  int*    cursor  = (int*)(tail + 8756);                     // 4096 B

  k_inv    <<<1, 64, 0, stream>>>(T, invT, flag);
  k_table  <<<512, 256, 0, stream>>>(centers, scales, weights, invT, flag, table, cnt, corner);
  k_count  <<<512, 256, 0, stream>>>(table, bubble, flag, cnt, corner);
  k_offsets<<<1, 2 * NBIN, 0, stream>>>(cnt, off, cursor);
  k_fill   <<<512, 256, 0, stream>>>(table, bubble, flag, cursor, entries);
  k_gather <<<1024, 256, 0, stream>>>(entries, off, corner, flag, d_out);
}